// Round 1
// baseline (5363.731 us; speedup 1.0000x reference)
//
#include <hip/hip_runtime.h>

static constexpr int BB  = 4;
static constexpr int SS  = 512;
static constexpr int DD  = 1024;
static constexpr int HH  = 16;
static constexpr int LL  = 4;
static constexpr int VV  = 32000;
static constexpr int DHH = 64;
static constexpr int FFF = 4096;

typedef short bf16x8  __attribute__((ext_vector_type(8)));
typedef short bf16x4v __attribute__((ext_vector_type(4)));
typedef float f32x4   __attribute__((ext_vector_type(4)));

__device__ __forceinline__ float b2f(ushort u){
  union { float f; unsigned int u32; } x; x.u32 = ((unsigned int)u) << 16; return x.f;
}
__device__ __forceinline__ ushort f2b(float f){
  union { float f; unsigned int u32; } x; x.f = f;
  unsigned int u = x.u32;
  return (ushort)((u + 0x7FFFu + ((u >> 16) & 1u)) >> 16);
}

// ---------------- weight convert + transpose: f32 [K][N] -> bf16 [N][K] ----------------
__global__ __launch_bounds__(256) void convT_k(const float* __restrict__ in, ushort* __restrict__ out,
                                               int K, int N, long inStride, long outStride)
{
  in  += (long)blockIdx.z * inStride;
  out += (long)blockIdx.z * outStride;
  __shared__ float tile[64][65];
  int n0 = blockIdx.x * 64, k0 = blockIdx.y * 64;
  int tid = threadIdx.x;
  int cc = tid & 63, rr = tid >> 6;
#pragma unroll
  for (int i = 0; i < 16; i++){
    int r = rr + i * 4;
    tile[r][cc] = in[(long)(k0 + r) * N + n0 + cc];
  }
  __syncthreads();
#pragma unroll
  for (int i = 0; i < 16; i++){
    int r = rr + i * 4;
    out[(long)(n0 + r) * K + k0 + cc] = f2b(tile[cc][r]);
  }
}

// ---------------- embedding: x = emb[ids] + pos_emb ; out_emb = emb[ids] ----------------
__global__ __launch_bounds__(256) void embed_k(const int* __restrict__ ids, const float* __restrict__ emb,
                                               const float* __restrict__ pe, float* __restrict__ x,
                                               float* __restrict__ oemb)
{
  long e4 = (long)blockIdx.x * 256 + threadIdx.x;   // over BB*SS*DD/4
  int d4 = (int)(e4 & 255);
  int t  = (int)((e4 >> 8) & 511);
  int b  = (int)(e4 >> 17);
  int id = ids[b * SS + t];
  float4 ev = *((const float4*)emb + (long)id * 256 + d4);
  float4 pv = *((const float4*)pe + (long)t * 256 + d4);
  float4 xv = make_float4(ev.x + pv.x, ev.y + pv.y, ev.z + pv.z, ev.w + pv.w);
  *((float4*)x + e4) = xv;
  float* op = oemb + e4 * 4;           // d_out+4B offset: scalar stores (not 16B aligned)
  op[0] = ev.x; op[1] = ev.y; op[2] = ev.z; op[3] = ev.w;
}

// ---------------- layernorm: f32 row -> bf16 row ----------------
__global__ __launch_bounds__(256) void ln_k(const float* __restrict__ xin, const float* __restrict__ g,
                                            const float* __restrict__ bt, ushort* __restrict__ out, int t0)
{
  int t = t0 + blockIdx.x, b = blockIdx.y, tid = threadIdx.x;
  const float* row = xin + ((long)b * SS + t) * DD;
  float4 v = *(const float4*)(row + tid * 4);
  float s1 = v.x + v.y + v.z + v.w;
  float s2 = v.x * v.x + v.y * v.y + v.z * v.z + v.w * v.w;
#pragma unroll
  for (int o = 32; o; o >>= 1){ s1 += __shfl_down(s1, o); s2 += __shfl_down(s2, o); }
  __shared__ float red[2][4];
  int wv = tid >> 6, lane = tid & 63;
  if (lane == 0){ red[0][wv] = s1; red[1][wv] = s2; }
  __syncthreads();
  s1 = red[0][0] + red[0][1] + red[0][2] + red[0][3];
  s2 = red[1][0] + red[1][1] + red[1][2] + red[1][3];
  float mean = s1 * (1.0f / DD);
  float var  = s2 * (1.0f / DD) - mean * mean;
  float rstd = rsqrtf(var + 1e-5f);
  float4 gv = *(const float4*)(g + tid * 4);
  float4 bv = *(const float4*)(bt + tid * 4);
  ushort4 o4;
  o4.x = f2b((v.x - mean) * rstd * gv.x + bv.x);
  o4.y = f2b((v.y - mean) * rstd * gv.y + bv.y);
  o4.z = f2b((v.z - mean) * rstd * gv.z + bv.z);
  o4.w = f2b((v.w - mean) * rstd * gv.w + bv.w);
  *(ushort4*)(out + ((long)b * SS + t) * DD + tid * 4) = o4;
}

// ---------------- GEMM: C[M,N] = A[M,K](bf16) * W(bf16,[N][K]) with epilogues ----------------
// EPI: 0 = bf16 out; 1 = f32 out += addend (in-place residual); 2 = gelu -> bf16; 3 = f32 out
template<int BM, int EPI>
__global__ __launch_bounds__(256) void gemm_k(const ushort* __restrict__ A, long strideAb, int lda,
                                              const ushort* __restrict__ BT,
                                              void* __restrict__ Cv, long strideCb, int ldc,
                                              const float* __restrict__ Add, long strideDb,
                                              int M, int K)
{
  constexpr int WR  = (BM == 128) ? 2 : 1;
  constexpr int WC  = (BM == 128) ? 2 : 4;
  constexpr int WMs = BM / WR;
  constexpr int WNs = 128 / WC;
  constexpr int MFR = WMs / 16;
  constexpr int NFR = WNs / 16;
  __shared__ ushort As[BM][72];
  __shared__ ushort Bs[128][72];
  int tid = threadIdx.x;
  int wv = tid >> 6, lane = tid & 63;
  int wm = wv / WC, wn = wv % WC;
  int m0 = blockIdx.x * BM;
  int n0 = blockIdx.y * 128;
  int bz = blockIdx.z;
  A += (long)bz * strideAb;
  float*  Cf = (float*)Cv  + (long)bz * strideCb;
  ushort* Cb = (ushort*)Cv + (long)bz * strideCb;
  const float* Addp = Add + (long)bz * strideDb;

  f32x4 acc[MFR][NFR];
  f32x4 zz = {0.f, 0.f, 0.f, 0.f};
#pragma unroll
  for (int m = 0; m < MFR; m++)
#pragma unroll
    for (int n = 0; n < NFR; n++) acc[m][n] = zz;

  int g4 = (lane >> 4) * 4;
  int rA = lane & 15;

  for (int k0 = 0; k0 < K; k0 += 64){
    if constexpr (BM == 128){
#pragma unroll
      for (int i = 0; i < 4; i++){
        int r = (tid >> 3) + i * 32;
        int c = (tid & 7) * 8;
        uint4 val = make_uint4(0u, 0u, 0u, 0u);
        int gr = m0 + r;
        if (gr < M) val = *(const uint4*)(A + (long)gr * lda + k0 + c);
        *(uint4*)&As[r][c] = val;
      }
    } else {
      int r = tid >> 4;
      int c = (tid & 15) * 4;
      uint2 val = make_uint2(0u, 0u);
      int gr = m0 + r;
      if (gr < M) val = *(const uint2*)(A + (long)gr * lda + k0 + c);
      *(uint2*)&As[r][c] = val;
    }
#pragma unroll
    for (int i = 0; i < 4; i++){
      int r = (tid >> 3) + i * 32;
      int c = (tid & 7) * 8;
      *(uint4*)&Bs[r][c] = *(const uint4*)(BT + (long)(n0 + r) * K + k0 + c);
    }
    __syncthreads();
#pragma unroll
    for (int kk = 0; kk < 64; kk += 32){
      bf16x8 af[MFR], bfr[NFR];
#pragma unroll
      for (int m = 0; m < MFR; m++){
        int row = wm * WMs + m * 16 + rA;
        bf16x4v lo = *(const bf16x4v*)&As[row][kk + g4];
        bf16x4v hi = *(const bf16x4v*)&As[row][kk + 16 + g4];
        af[m] = __builtin_shufflevector(lo, hi, 0, 1, 2, 3, 4, 5, 6, 7);
      }
#pragma unroll
      for (int n = 0; n < NFR; n++){
        int row = wn * WNs + n * 16 + rA;
        bf16x4v lo = *(const bf16x4v*)&Bs[row][kk + g4];
        bf16x4v hi = *(const bf16x4v*)&Bs[row][kk + 16 + g4];
        bfr[n] = __builtin_shufflevector(lo, hi, 0, 1, 2, 3, 4, 5, 6, 7);
      }
#pragma unroll
      for (int m = 0; m < MFR; m++)
#pragma unroll
        for (int n = 0; n < NFR; n++)
          acc[m][n] = __builtin_amdgcn_mfma_f32_16x16x32_bf16(af[m], bfr[n], acc[m][n], 0, 0, 0);
    }
    __syncthreads();
  }

  int r4 = (lane >> 4) * 4;
#pragma unroll
  for (int m = 0; m < MFR; m++){
#pragma unroll
    for (int n = 0; n < NFR; n++){
      int orow = wm * WMs + m * 16 + r4;
      int ocol = n0 + wn * WNs + n * 16 + rA;
#pragma unroll
      for (int r = 0; r < 4; r++){
        int grow = m0 + orow + r;
        if (grow < M){
          long idx = (long)grow * ldc + ocol;
          float v = acc[m][n][r];
          if (EPI == 1) v += Addp[idx];
          if (EPI == 2){
            float tt = 0.7978845608028654f * (v + 0.044715f * v * v * v);
            v = 0.5f * v * (1.0f + tanhf(tt));
          }
          if (EPI == 0 || EPI == 2) Cb[idx] = f2b(v);
          else Cf[idx] = v;
        }
      }
    }
  }
}

// ---------------- append chunk K/V into cache [L][B][H][S][DH] ----------------
__global__ __launch_bounds__(256) void kvcopy_k(const ushort* __restrict__ qkv, ushort* __restrict__ kc,
                                                ushort* __restrict__ vc, int l, int t0)
{
  int t = t0 + blockIdx.x, b = blockIdx.y, tid = threadIdx.x;
  const ushort* src = qkv + ((long)b * SS + t) * (3 * DD) + DD;
#pragma unroll
  for (int i = 0; i < 8; i++){
    int e = tid + i * 256;          // 0..2047
    ushort val = src[e];
    int isv = e >> 10, ee = e & 1023;
    int h = ee >> 6, d = ee & 63;
    long dst = (((long)l * BB + b) * HH + h) * ((long)SS * DHH) + (long)t * DHH + d;
    if (isv) vc[dst] = val; else kc[dst] = val;
  }
}

// ---------------- attention: one wave per (b,h,q-row), scores in LDS ----------------
__global__ __launch_bounds__(256) void attn_k(const ushort* __restrict__ qkv, const ushort* __restrict__ kc,
                                              const ushort* __restrict__ vc, ushort* __restrict__ o,
                                              int l, int t0, int Tc)
{
  __shared__ float sc[4][512];
  __shared__ float qs[4][64];
  int tid = threadIdx.x, wv = tid >> 6, lane = tid & 63;
  int b = blockIdx.z, h = blockIdx.y;
  int qrow = blockIdx.x * 4 + wv;
  bool act = qrow < Tc;
  int tq = t0 + qrow;
  long kvoff = (((long)l * BB + b) * HH + h) * ((long)SS * DHH);
  const ushort* kb = kc + kvoff;
  const ushort* vb = vc + kvoff;
  if (act) qs[wv][lane] = b2f(qkv[((long)b * SS + tq) * (3 * DD) + h * DHH + lane]);
  __syncthreads();
  int nk = act ? (tq + 1) : 0;
  float m = -3.0e38f;
  for (int key = lane; key < nk; key += 64){
    const ushort* kp = kb + (long)key * DHH;
    float s = 0.f;
#pragma unroll
    for (int j = 0; j < 8; j++){
      uint4 kvv = *(const uint4*)(kp + j * 8);
      s += qs[wv][j*8+0] * b2f((ushort)(kvv.x & 0xffff));
      s += qs[wv][j*8+1] * b2f((ushort)(kvv.x >> 16));
      s += qs[wv][j*8+2] * b2f((ushort)(kvv.y & 0xffff));
      s += qs[wv][j*8+3] * b2f((ushort)(kvv.y >> 16));
      s += qs[wv][j*8+4] * b2f((ushort)(kvv.z & 0xffff));
      s += qs[wv][j*8+5] * b2f((ushort)(kvv.z >> 16));
      s += qs[wv][j*8+6] * b2f((ushort)(kvv.w & 0xffff));
      s += qs[wv][j*8+7] * b2f((ushort)(kvv.w >> 16));
    }
    s *= 0.125f;
    sc[wv][key] = s;
    m = fmaxf(m, s);
  }
#pragma unroll
  for (int off = 32; off; off >>= 1) m = fmaxf(m, __shfl_xor(m, off));
  float ssum = 0.f;
  for (int key = lane; key < nk; key += 64){
    float p = expf(sc[wv][key] - m);
    sc[wv][key] = p;
    ssum += p;
  }
#pragma unroll
  for (int off = 32; off; off >>= 1) ssum += __shfl_xor(ssum, off);
  __syncthreads();   // make per-wave sc[] visible cross-lane
  float accv = 0.f;
  for (int key = 0; key < nk; key++)
    accv += sc[wv][key] * b2f(vb[(long)key * DHH + lane]);
  if (act) o[((long)b * SS + tq) * DD + h * DHH + lane] = f2b(accv / ssum);
}

// ---------------- feedback: embedding[pos] = hid[pos-1]; x[pos] = hid[pos-1] + pos_emb[pos] ----------------
__global__ __launch_bounds__(256) void advance_k(const ushort* __restrict__ hid, const float* __restrict__ pe,
                                                 float* __restrict__ x, float* __restrict__ oemb, int pos)
{
  int d = blockIdx.x * 256 + threadIdx.x;
  int b = blockIdx.y;
  float hv = b2f(hid[((long)b * SS + pos - 1) * DD + d]);
  oemb[((long)b * SS + pos) * DD + d] = hv;
  x[((long)b * SS + pos) * DD + d] = hv + pe[(long)pos * DD + d];
}

// ---------------- loss ----------------
__global__ __launch_bounds__(256) void loss_rows_k(const float* __restrict__ logits, const int* __restrict__ labels,
                                                   float* __restrict__ rowloss)
{
  int t = blockIdx.x, b = blockIdx.y, tid = threadIdx.x;
  const float* row = logits + ((long)b * SS + t) * VV;
  float m = -3.0e38f, s = 0.f;
  for (int i = tid; i < VV; i += 256){
    float v = row[i];
    if (v > m){ s = s * expf(m - v) + 1.f; m = v; }
    else s += expf(v - m);
  }
  __shared__ float sm[256], ssb[256];
  sm[tid] = m; ssb[tid] = s;
  __syncthreads();
  if (tid == 0){
    float M = -3.0e38f;
    for (int i = 0; i < 256; i++) M = fmaxf(M, sm[i]);
    float Ssum = 0.f;
    for (int i = 0; i < 256; i++) Ssum += ssb[i] * expf(sm[i] - M);
    int lab = labels[b * SS + t + 1];
    float xl = row[lab];
    rowloss[b * (SS - 1) + t] = (M + logf(Ssum)) - xl;
  }
}

__global__ __launch_bounds__(256) void loss_final_k(const float* __restrict__ rowloss, float* __restrict__ out)
{
  int tid = threadIdx.x;
  float s = 0.f;
  for (int i = tid; i < BB * (SS - 1); i += 256) s += rowloss[i];
#pragma unroll
  for (int o = 32; o; o >>= 1) s += __shfl_down(s, o);
  __shared__ float red[4];
  if ((tid & 63) == 0) red[tid >> 6] = s;
  __syncthreads();
  if (tid == 0) out[0] = (red[0] + red[1] + red[2] + red[3]) / (float)(BB * (SS - 1));
}

// ---------------- host ----------------
static inline int cdiv_i(int a, int b){ return (a + b - 1) / b; }

#define LAUNCH_GEMM(EPIv, Aptr, ldav, BTptr, Cptr, ldcv, Addptr, Kv, Nv)                                  \
  do {                                                                                                    \
    if (Tc >= 128)                                                                                        \
      gemm_k<128, EPIv><<<dim3(cdiv_i(Tc, 128), (Nv) / 128, BB), dim3(256), 0, stream>>>(                 \
        (const ushort*)(Aptr), (long)SS * (ldav), (ldav), (const ushort*)(BTptr),                         \
        (void*)(Cptr), (long)SS * (ldcv), (ldcv), (const float*)(Addptr), (long)SS * (ldcv), Tc, (Kv));   \
    else                                                                                                  \
      gemm_k<16, EPIv><<<dim3(cdiv_i(Tc, 16), (Nv) / 128, BB), dim3(256), 0, stream>>>(                   \
        (const ushort*)(Aptr), (long)SS * (ldav), (ldav), (const ushort*)(BTptr),                         \
        (void*)(Cptr), (long)SS * (ldcv), (ldcv), (const float*)(Addptr), (long)SS * (ldcv), Tc, (Kv));   \
  } while (0)

extern "C" void kernel_launch(void* const* d_in, const int* in_sizes, int n_in,
                              void* d_out, int out_size, void* d_ws, size_t ws_size,
                              hipStream_t stream)
{
  (void)in_sizes; (void)n_in; (void)out_size; (void)ws_size;
  const int*   ids    = (const int*)d_in[0];
  const int*   labels = (const int*)d_in[2];
  const float* emb    = (const float*)d_in[4];
  const float* pe     = (const float*)d_in[5];
  const float* Wqkv   = (const float*)d_in[6];
  const float* Wo     = (const float*)d_in[7];
  const float* W1     = (const float*)d_in[8];
  const float* W2     = (const float*)d_in[9];
  const float* ln1g   = (const float*)d_in[10];
  const float* ln1b   = (const float*)d_in[11];
  const float* ln2g   = (const float*)d_in[12];
  const float* ln2b   = (const float*)d_in[13];
  const float* lnfg   = (const float*)d_in[14];
  const float* lnfb   = (const float*)d_in[15];
  const float* lm     = (const float*)d_in[16];

  float* out_loss   = (float*)d_out;
  float* out_emb    = out_loss + 1;
  float* out_logits = out_emb + (size_t)BB * SS * DD;

  char* wsp = (char*)d_ws;
  size_t off = 0;
  auto alloc = [&](size_t bytes) -> void* {
    void* p = wsp + off; off += (bytes + 255) & ~(size_t)255; return p;
  };
  ushort* wqkvT = (ushort*)alloc((size_t)LL * 3 * DD * DD * 2);
  ushort* woT   = (ushort*)alloc((size_t)LL * DD * DD * 2);
  ushort* w1T   = (ushort*)alloc((size_t)LL * FFF * DD * 2);
  ushort* w2T   = (ushort*)alloc((size_t)LL * DD * FFF * 2);
  ushort* lmT   = (ushort*)alloc((size_t)VV * DD * 2);
  float*  x     = (float*)alloc((size_t)BB * SS * DD * 4);
  ushort* hbuf  = (ushort*)alloc((size_t)BB * SS * DD * 2);
  ushort* qkv   = (ushort*)alloc((size_t)BB * SS * 3 * DD * 2);
  ushort* obuf  = (ushort*)alloc((size_t)BB * SS * DD * 2);
  ushort* gbuf  = (ushort*)alloc((size_t)BB * SS * FFF * 2);
  ushort* hid   = (ushort*)alloc((size_t)BB * SS * DD * 2);
  ushort* kcache= (ushort*)alloc((size_t)LL * BB * SS * DD * 2);
  ushort* vcache= (ushort*)alloc((size_t)LL * BB * SS * DD * 2);
  float*  rowls = (float*)alloc((size_t)BB * (SS - 1) * 4);

  // ---- weights -> bf16 transposed [N][K] ----
  convT_k<<<dim3(3 * DD / 64, DD / 64, LL), dim3(256), 0, stream>>>(Wqkv, wqkvT, DD, 3 * DD, (long)DD * 3 * DD, (long)3 * DD * DD);
  convT_k<<<dim3(DD / 64, DD / 64, LL),     dim3(256), 0, stream>>>(Wo,   woT,  DD, DD,     (long)DD * DD,     (long)DD * DD);
  convT_k<<<dim3(FFF / 64, DD / 64, LL),    dim3(256), 0, stream>>>(W1,   w1T,  DD, FFF,    (long)DD * FFF,    (long)FFF * DD);
  convT_k<<<dim3(DD / 64, FFF / 64, LL),    dim3(256), 0, stream>>>(W2,   w2T,  FFF, DD,    (long)FFF * DD,    (long)DD * FFF);
  convT_k<<<dim3(VV / 64, DD / 64, 1),      dim3(256), 0, stream>>>(lm,   lmT,  DD, VV,     0, 0);

  embed_k<<<dim3(BB * SS * DD / 4 / 256), dim3(256), 0, stream>>>(ids, emb, pe, x, out_emb);

  const int ct0[7] = {0, 64, 65, 66, 67, 68, 69};
  const int ct1[7] = {64, 65, 66, 67, 68, 69, 512};

  for (int c = 0; c < 7; c++){
    int t0 = ct0[c];
    int Tc = ct1[c] - t0;
    for (int l = 0; l < LL; l++){
      ln_k<<<dim3(Tc, BB), dim3(256), 0, stream>>>(x, ln1g + l * DD, ln1b + l * DD, hbuf, t0);
      LAUNCH_GEMM(0, hbuf + (long)t0 * DD, DD, wqkvT + (long)l * 3 * DD * DD,
                  qkv + (long)t0 * 3 * DD, 3 * DD, x, DD, 3 * DD);
      kvcopy_k<<<dim3(Tc, BB), dim3(256), 0, stream>>>(qkv, kcache, vcache, l, t0);
      attn_k<<<dim3(cdiv_i(Tc, 4), HH, BB), dim3(256), 0, stream>>>(qkv, kcache, vcache, obuf, l, t0, Tc);
      LAUNCH_GEMM(1, obuf + (long)t0 * DD, DD, woT + (long)l * DD * DD,
                  x + (long)t0 * DD, DD, x + (long)t0 * DD, DD, DD);
      ln_k<<<dim3(Tc, BB), dim3(256), 0, stream>>>(x, ln2g + l * DD, ln2b + l * DD, hbuf, t0);
      LAUNCH_GEMM(2, hbuf + (long)t0 * DD, DD, w1T + (long)l * FFF * DD,
                  gbuf + (long)t0 * FFF, FFF, x, DD, FFF);
      LAUNCH_GEMM(1, gbuf + (long)t0 * FFF, FFF, w2T + (long)l * DD * FFF,
                  x + (long)t0 * DD, DD, x + (long)t0 * DD, FFF, DD);
    }
    ln_k<<<dim3(Tc, BB), dim3(256), 0, stream>>>(x, lnfg, lnfb, hid, t0);
    LAUNCH_GEMM(3, hid + (long)t0 * DD, DD, lmT,
                out_logits + (long)t0 * VV, VV, x, DD, VV);
    if (c < 6)
      advance_k<<<dim3(DD / 256, BB), dim3(256), 0, stream>>>(hid, pe, x, out_emb, 64 + c);
  }

  loss_rows_k<<<dim3(SS - 1, BB), dim3(256), 0, stream>>>(out_logits, labels, rowls);
  loss_final_k<<<dim3(1), dim3(256), 0, stream>>>(rowls, out_loss);
}

// Round 3
// 4789.675 us; speedup vs baseline: 1.1199x; 1.1199x over previous
//
#include <hip/hip_runtime.h>

static constexpr int BB  = 4;
static constexpr int SS  = 512;
static constexpr int DD  = 1024;
static constexpr int HH  = 16;
static constexpr int LL  = 4;
static constexpr int VV  = 32000;
static constexpr int DHH = 64;
static constexpr int FFF = 4096;

typedef short bf16x8  __attribute__((ext_vector_type(8)));
typedef short bf16x4v __attribute__((ext_vector_type(4)));
typedef float f32x4   __attribute__((ext_vector_type(4)));

__device__ __forceinline__ float b2f(ushort u){
  union { float f; unsigned int u32; } x; x.u32 = ((unsigned int)u) << 16; return x.f;
}
__device__ __forceinline__ ushort f2b(float f){
  union { float f; unsigned int u32; } x; x.f = f;
  unsigned int u = x.u32;
  return (ushort)((u + 0x7FFFu + ((u >> 16) & 1u)) >> 16);
}

// ---------------- weight convert + transpose: f32 [K][N] -> bf16 [N][K] ----------------
__global__ __launch_bounds__(256) void convT_k(const float* __restrict__ in, ushort* __restrict__ out,
                                               int K, int N, long inStride, long outStride)
{
  in  += (long)blockIdx.z * inStride;
  out += (long)blockIdx.z * outStride;
  __shared__ float tile[64][65];
  int n0 = blockIdx.x * 64, k0 = blockIdx.y * 64;
  int tid = threadIdx.x;
  int cc = tid & 63, rr = tid >> 6;
#pragma unroll
  for (int i = 0; i < 16; i++){
    int r = rr + i * 4;
    tile[r][cc] = in[(long)(k0 + r) * N + n0 + cc];
  }
  __syncthreads();
#pragma unroll
  for (int i = 0; i < 16; i++){
    int r = rr + i * 4;
    out[(long)(n0 + r) * K + k0 + cc] = f2b(tile[cc][r]);
  }
}

// ---------------- embedding (token-major x, b-major out_emb) ----------------
__global__ __launch_bounds__(256) void embed_k(const int* __restrict__ ids, const float* __restrict__ emb,
                                               const float* __restrict__ pe, float* __restrict__ x,
                                               float* __restrict__ oemb)
{
  int t = blockIdx.x, b = blockIdx.y, tid = threadIdx.x;
  int id = ids[b * SS + t];
  float4 ev = *((const float4*)(emb + (long)id * DD) + tid);
  float4 pv = *((const float4*)(pe  + (long)t  * DD) + tid);
  *((float4*)(x + (long)(t * BB + b) * DD) + tid) =
      make_float4(ev.x + pv.x, ev.y + pv.y, ev.z + pv.z, ev.w + pv.w);
  float* op = oemb + ((long)b * SS + t) * DD + tid * 4;   // d_out+4B: scalar stores
  op[0] = ev.x; op[1] = ev.y; op[2] = ev.z; op[3] = ev.w;
}

// ---------------- layernorm: f32 row -> bf16 row (row-indexed, token-major) ----------------
__global__ __launch_bounds__(256) void ln_k(const float* __restrict__ xin, const float* __restrict__ g,
                                            const float* __restrict__ bt, ushort* __restrict__ out, long row0)
{
  long row = row0 + blockIdx.x;
  int tid = threadIdx.x;
  const float* rp = xin + row * DD;
  float4 v = *(const float4*)(rp + tid * 4);
  float s1 = v.x + v.y + v.z + v.w;
  float s2 = v.x * v.x + v.y * v.y + v.z * v.z + v.w * v.w;
#pragma unroll
  for (int o = 32; o; o >>= 1){ s1 += __shfl_down(s1, o); s2 += __shfl_down(s2, o); }
  __shared__ float red[2][4];
  int wv = tid >> 6, lane = tid & 63;
  if (lane == 0){ red[0][wv] = s1; red[1][wv] = s2; }
  __syncthreads();
  s1 = red[0][0] + red[0][1] + red[0][2] + red[0][3];
  s2 = red[1][0] + red[1][1] + red[1][2] + red[1][3];
  float mean = s1 * (1.0f / DD);
  float var  = s2 * (1.0f / DD) - mean * mean;
  float rstd = rsqrtf(var + 1e-5f);
  float4 gv = *(const float4*)(g + tid * 4);
  float4 bv = *(const float4*)(bt + tid * 4);
  ushort4 o4;
  o4.x = f2b((v.x - mean) * rstd * gv.x + bv.x);
  o4.y = f2b((v.y - mean) * rstd * gv.y + bv.y);
  o4.z = f2b((v.z - mean) * rstd * gv.z + bv.z);
  o4.w = f2b((v.w - mean) * rstd * gv.w + bv.w);
  *(ushort4*)(out + row * DD + tid * 4) = o4;
}

// ---------------- shared epilogue ----------------
// EPI 1: f32 residual add (token-major, in-place)   2: gelu -> bf16 (token-major)
// EPI 3: f32 logits scatter to [B][S][V]            4: qkv -> q buf + kv cache
// EPI 5: raw f32 partial (ldc = N)
// NOTE: no __restrict__ on Cv/Add anywhere — they alias (x == x) in EPI 1.
template<int EPI>
__device__ __forceinline__ void epi_store(float v, int grow, int ocol, void* Cv, int ldc,
                                          const float* Add, int t0, int l,
                                          ushort* kc, ushort* vc, ushort* qb)
{
  if constexpr (EPI == 1){
    float* Cf = (float*)Cv; long idx = (long)grow * ldc + ocol;
    Cf[idx] = v + Add[idx];
  } else if constexpr (EPI == 2){
    ushort* Cb = (ushort*)Cv; long idx = (long)grow * ldc + ocol;
    float tt = 0.7978845608028654f * (v + 0.044715f * v * v * v);
    Cb[idx] = f2b(0.5f * v * (1.0f + tanhf(tt)));
  } else if constexpr (EPI == 3){
    int t = t0 + (grow >> 2), b = grow & 3;
    ((float*)Cv)[((long)b * SS + t) * VV + ocol] = v;
  } else if constexpr (EPI == 4){
    if (ocol < DD){
      qb[((long)(t0 * BB + grow)) * DD + ocol] = f2b(v);
    } else {
      int t = t0 + (grow >> 2), b = grow & 3;
      int h = (ocol >> 6) & 15, d = ocol & 63;
      long dst = (((long)l * BB + b) * HH + h) * ((long)SS * DHH) + (long)t * DHH + d;
      if (ocol >= 2 * DD) vc[dst] = f2b(v); else kc[dst] = f2b(v);
    }
  } else {
    ((float*)Cv)[(long)grow * ldc + ocol] = v;
  }
}

// ---------------- GEMM: C[M,N] = A[M,K](bf16) * W(bf16,[N][K]) ----------------
// Reg-staged LDS (replay-validated in round 1), padded [72] rows.
// Grid is 1-D (gx*gy for EPI!=5; KS*gy for EPI==5), bijective XCD swizzle.
template<int BM, int EPI>
__global__ __launch_bounds__(256) void gemm_k(const ushort* __restrict__ A, int lda,
                                              const ushort* __restrict__ BT,
                                              void* Cv, int ldc,
                                              const float* Add,
                                              int M, int N, int K, int gx, int Kc,
                                              int l, int t0,
                                              ushort* kc, ushort* vc, ushort* qb)
{
  constexpr bool SPLIT = (EPI == 5);
  constexpr int WR  = (BM == 128) ? 2 : 1;
  constexpr int WC  = (BM == 128) ? 2 : 4;
  constexpr int WMs = BM / WR;
  constexpr int WNs = 128 / WC;
  constexpr int MFR = WMs / 16;
  constexpr int NFR = WNs / 16;
  __shared__ ushort As[BM][72];
  __shared__ ushort Bs[128][72];
  int tid = threadIdx.x;
  int wv = tid >> 6, lane = tid & 63;
  int wm = wv / WC, wn = wv % WC;

  // bijective XCD swizzle (m204)
  int nwg = gridDim.x, orig = blockIdx.x;
  int qq = nwg >> 3, rr8 = nwg & 7, xcd = orig & 7;
  int wgid = ((xcd < rr8) ? xcd * (qq + 1) : rr8 * (qq + 1) + (xcd - rr8) * qq) + (orig >> 3);

  int bx, by, k_beg, k_end;
  if constexpr (SPLIT){
    int gy = N >> 7;
    int ks = wgid / gy; by = wgid - ks * gy; bx = 0;
    k_beg = ks * Kc; k_end = k_beg + Kc;
    Cv = (void*)((float*)Cv + (long)ks * M * N);
  } else {
    bx = wgid % gx; by = wgid / gx;
    k_beg = 0; k_end = K;
  }
  int m0 = bx * BM, n0 = by * 128;

  f32x4 acc[MFR][NFR];
  f32x4 zz = {0.f, 0.f, 0.f, 0.f};
#pragma unroll
  for (int m = 0; m < MFR; m++)
#pragma unroll
    for (int n = 0; n < NFR; n++) acc[m][n] = zz;

  int g4 = (lane >> 4) * 4;
  int rA = lane & 15;

  for (int k0 = k_beg; k0 < k_end; k0 += 64){
    if constexpr (BM == 128){
#pragma unroll
      for (int i = 0; i < 4; i++){
        int r = (tid >> 3) + i * 32;
        int c = (tid & 7) * 8;
        uint4 val = make_uint4(0u, 0u, 0u, 0u);
        int gr = m0 + r;
        if (gr < M) val = *(const uint4*)(A + (long)gr * lda + k0 + c);
        *(uint4*)&As[r][c] = val;
      }
    } else {
      int r = tid >> 4;
      int c = (tid & 15) * 4;
      uint2 val = make_uint2(0u, 0u);
      int gr = m0 + r;
      if (gr < M) val = *(const uint2*)(A + (long)gr * lda + k0 + c);
      *(uint2*)&As[r][c] = val;
    }
#pragma unroll
    for (int i = 0; i < 4; i++){
      int r = (tid >> 3) + i * 32;
      int c = (tid & 7) * 8;
      *(uint4*)&Bs[r][c] = *(const uint4*)(BT + (long)(n0 + r) * K + k0 + c);
    }
    __syncthreads();
#pragma unroll
    for (int kk = 0; kk < 64; kk += 32){
      bf16x8 af[MFR], bfr[NFR];
#pragma unroll
      for (int m = 0; m < MFR; m++){
        int row = wm * WMs + m * 16 + rA;
        bf16x4v lo = *(const bf16x4v*)&As[row][kk + g4];
        bf16x4v hi = *(const bf16x4v*)&As[row][kk + 16 + g4];
        af[m] = __builtin_shufflevector(lo, hi, 0, 1, 2, 3, 4, 5, 6, 7);
      }
#pragma unroll
      for (int n = 0; n < NFR; n++){
        int row = wn * WNs + n * 16 + rA;
        bf16x4v lo = *(const bf16x4v*)&Bs[row][kk + g4];
        bf16x4v hi = *(const bf16x4v*)&Bs[row][kk + 16 + g4];
        bfr[n] = __builtin_shufflevector(lo, hi, 0, 1, 2, 3, 4, 5, 6, 7);
      }
#pragma unroll
      for (int m = 0; m < MFR; m++)
#pragma unroll
        for (int n = 0; n < NFR; n++)
          acc[m][n] = __builtin_amdgcn_mfma_f32_16x16x32_bf16(af[m], bfr[n], acc[m][n], 0, 0, 0);
    }
    __syncthreads();
  }

  int r4 = (lane >> 4) * 4;
#pragma unroll
  for (int m = 0; m < MFR; m++){
#pragma unroll
    for (int n = 0; n < NFR; n++){
      int orow = wm * WMs + m * 16 + r4;
      int ocol = n0 + wn * WNs + n * 16 + rA;
#pragma unroll
      for (int r = 0; r < 4; r++){
        int grow = m0 + orow + r;
        if (grow < M)
          epi_store<EPI>(acc[m][n][r], grow, ocol, Cv, ldc, Add, t0, l, kc, vc, qb);
      }
    }
  }
}

// ---------------- split-K reduce ----------------
template<int EPI>
__global__ __launch_bounds__(256) void sred_k(const float* __restrict__ part, int KS, int M, int N,
                                              void* Cv, int ldc, const float* Add,
                                              int l, int t0, ushort* kc,
                                              ushort* vc, ushort* qb)
{
  int i = blockIdx.x * 256 + threadIdx.x;
  if (i >= M * N) return;
  long MN = (long)M * N;
  float v = 0.f;
  for (int s = 0; s < KS; s++) v += part[s * MN + i];
  int m = i / N, n = i - m * N;
  epi_store<EPI>(v, m, n, Cv, ldc, Add, t0, l, kc, vc, qb);
}

// ---------------- attention (token-major q/o, cached k/v) ----------------
__global__ __launch_bounds__(256) void attn_k(const ushort* __restrict__ qb, const ushort* __restrict__ kc,
                                              const ushort* __restrict__ vc, ushort* __restrict__ o,
                                              int l, int t0, int Tc)
{
  __shared__ float sc[4][512];
  __shared__ float qs[4][64];
  int tid = threadIdx.x, wv = tid >> 6, lane = tid & 63;
  int b = blockIdx.z, h = blockIdx.y;
  int qrow = blockIdx.x * 4 + wv;
  bool act = qrow < Tc;
  int tq = t0 + qrow;
  long kvoff = (((long)l * BB + b) * HH + h) * ((long)SS * DHH);
  const ushort* kb = kc + kvoff;
  const ushort* vb = vc + kvoff;
  if (act) qs[wv][lane] = b2f(qb[((long)(tq * BB + b)) * DD + h * DHH + lane]);
  __syncthreads();
  int nk = act ? (tq + 1) : 0;
  float m = -3.0e38f;
  for (int key = lane; key < nk; key += 64){
    const ushort* kp = kb + (long)key * DHH;
    float s = 0.f;
#pragma unroll
    for (int j = 0; j < 8; j++){
      uint4 kvv = *(const uint4*)(kp + j * 8);
      s += qs[wv][j*8+0] * b2f((ushort)(kvv.x & 0xffff));
      s += qs[wv][j*8+1] * b2f((ushort)(kvv.x >> 16));
      s += qs[wv][j*8+2] * b2f((ushort)(kvv.y & 0xffff));
      s += qs[wv][j*8+3] * b2f((ushort)(kvv.y >> 16));
      s += qs[wv][j*8+4] * b2f((ushort)(kvv.z & 0xffff));
      s += qs[wv][j*8+5] * b2f((ushort)(kvv.z >> 16));
      s += qs[wv][j*8+6] * b2f((ushort)(kvv.w & 0xffff));
      s += qs[wv][j*8+7] * b2f((ushort)(kvv.w >> 16));
    }
    s *= 0.125f;
    sc[wv][key] = s;
    m = fmaxf(m, s);
  }
#pragma unroll
  for (int off = 32; off; off >>= 1) m = fmaxf(m, __shfl_xor(m, off));
  float ssum = 0.f;
  for (int key = lane; key < nk; key += 64){
    float p = expf(sc[wv][key] - m);
    sc[wv][key] = p;
    ssum += p;
  }
#pragma unroll
  for (int off = 32; off; off >>= 1) ssum += __shfl_xor(ssum, off);
  __syncthreads();
  float accv = 0.f;
  for (int key = 0; key < nk; key++)
    accv += sc[wv][key] * b2f(vb[(long)key * DHH + lane]);
  if (act) o[((long)(tq * BB + b)) * DD + h * DHH + lane] = f2b(accv / ssum);
}

// ---------------- feedback ----------------
__global__ __launch_bounds__(256) void advance_k(const ushort* __restrict__ hid, const float* __restrict__ pe,
                                                 float* __restrict__ x, float* __restrict__ oemb, int pos)
{
  int d = blockIdx.x * 256 + threadIdx.x;
  int b = blockIdx.y;
  float hv = b2f(hid[((long)((pos - 1) * BB + b)) * DD + d]);
  oemb[((long)b * SS + pos) * DD + d] = hv;
  x[((long)(pos * BB + b)) * DD + d] = hv + pe[(long)pos * DD + d];
}

// ---------------- loss ----------------
__global__ __launch_bounds__(256) void loss_rows_k(const float* __restrict__ logits, const int* __restrict__ labels,
                                                   float* __restrict__ rowloss)
{
  int t = blockIdx.x, b = blockIdx.y, tid = threadIdx.x;
  const float* row = logits + ((long)b * SS + t) * VV;
  float m = -3.0e38f, s = 0.f;
  for (int i = tid; i < VV; i += 256){
    float v = row[i];
    if (v > m){ s = s * expf(m - v) + 1.f; m = v; }
    else s += expf(v - m);
  }
  __shared__ float sm[256], ssb[256];
  sm[tid] = m; ssb[tid] = s;
  __syncthreads();
  if (tid == 0){
    float M = -3.0e38f;
    for (int i = 0; i < 256; i++) M = fmaxf(M, sm[i]);
    float Ssum = 0.f;
    for (int i = 0; i < 256; i++) Ssum += ssb[i] * expf(sm[i] - M);
    int lab = labels[b * SS + t + 1];
    float xl = row[lab];
    rowloss[b * (SS - 1) + t] = (M + logf(Ssum)) - xl;
  }
}

__global__ __launch_bounds__(256) void loss_final_k(const float* __restrict__ rowloss, float* __restrict__ out)
{
  int tid = threadIdx.x;
  float s = 0.f;
  for (int i = tid; i < BB * (SS - 1); i += 256) s += rowloss[i];
#pragma unroll
  for (int o = 32; o; o >>= 1) s += __shfl_down(s, o);
  __shared__ float red[4];
  if ((tid & 63) == 0) red[tid >> 6] = s;
  __syncthreads();
  if (tid == 0) out[0] = (red[0] + red[1] + red[2] + red[3]) / (float)(BB * (SS - 1));
}

// ---------------- host ----------------
static inline int cdiv_i(int a, int b){ return (a + b - 1) / b; }

extern "C" void kernel_launch(void* const* d_in, const int* in_sizes, int n_in,
                              void* d_out, int out_size, void* d_ws, size_t ws_size,
                              hipStream_t stream)
{
  (void)in_sizes; (void)n_in; (void)out_size; (void)ws_size;
  const int*   ids    = (const int*)d_in[0];
  const int*   labels = (const int*)d_in[2];
  const float* emb    = (const float*)d_in[4];
  const float* pe     = (const float*)d_in[5];
  const float* Wqkv   = (const float*)d_in[6];
  const float* Wo     = (const float*)d_in[7];
  const float* W1     = (const float*)d_in[8];
  const float* W2     = (const float*)d_in[9];
  const float* ln1g   = (const float*)d_in[10];
  const float* ln1b   = (const float*)d_in[11];
  const float* ln2g   = (const float*)d_in[12];
  const float* ln2b   = (const float*)d_in[13];
  const float* lnfg   = (const float*)d_in[14];
  const float* lnfb   = (const float*)d_in[15];
  const float* lm     = (const float*)d_in[16];

  float* out_loss   = (float*)d_out;
  float* out_emb    = out_loss + 1;
  float* out_logits = out_emb + (size_t)BB * SS * DD;

  char* wsp = (char*)d_ws;
  size_t off = 0;
  auto alloc = [&](size_t bytes) -> void* {
    void* p = wsp + off; off += (bytes + 255) & ~(size_t)255; return p;
  };
  ushort* wqkvT = (ushort*)alloc((size_t)LL * 3 * DD * DD * 2);
  ushort* woT   = (ushort*)alloc((size_t)LL * DD * DD * 2);
  ushort* w1T   = (ushort*)alloc((size_t)LL * FFF * DD * 2);
  ushort* w2T   = (ushort*)alloc((size_t)LL * DD * FFF * 2);
  ushort* lmT   = (ushort*)alloc((size_t)VV * DD * 2);
  float*  x     = (float*)alloc((size_t)BB * SS * DD * 4);
  ushort* hbuf  = (ushort*)alloc((size_t)BB * SS * DD * 2);
  ushort* qbuf  = (ushort*)alloc((size_t)BB * SS * DD * 2);
  ushort* obuf  = (ushort*)alloc((size_t)BB * SS * DD * 2);
  ushort* gbuf  = (ushort*)alloc((size_t)BB * SS * FFF * 2);
  ushort* hid   = (ushort*)alloc((size_t)BB * SS * DD * 2);
  ushort* kcache= (ushort*)alloc((size_t)LL * BB * SS * DD * 2);
  ushort* vcache= (ushort*)alloc((size_t)LL * BB * SS * DD * 2);
  float*  part  = (float*)alloc((size_t)16 * BB * FFF * 4);
  float*  rowls = (float*)alloc((size_t)BB * (SS - 1) * 4);

  convT_k<<<dim3(3 * DD / 64, DD / 64, LL), dim3(256), 0, stream>>>(Wqkv, wqkvT, DD, 3 * DD, (long)DD * 3 * DD, (long)3 * DD * DD);
  convT_k<<<dim3(DD / 64, DD / 64, LL),     dim3(256), 0, stream>>>(Wo,   woT,  DD, DD,     (long)DD * DD,     (long)DD * DD);
  convT_k<<<dim3(FFF / 64, DD / 64, LL),    dim3(256), 0, stream>>>(W1,   w1T,  DD, FFF,    (long)DD * FFF,    (long)FFF * DD);
  convT_k<<<dim3(DD / 64, FFF / 64, LL),    dim3(256), 0, stream>>>(W2,   w2T,  FFF, DD,    (long)FFF * DD,    (long)DD * FFF);
  convT_k<<<dim3(VV / 64, DD / 64, 1),      dim3(256), 0, stream>>>(lm,   lmT,  DD, VV,     0, 0);

  embed_k<<<dim3(SS, BB), dim3(256), 0, stream>>>(ids, emb, pe, x, out_emb);

  const int ct0[7] = {0, 64, 65, 66, 67, 68, 69};
  const int ct1[7] = {64, 65, 66, 67, 68, 69, 512};

  // big-GEMM launcher (BM=128, 1-D swizzled grid)
  auto g128 = [&](int epi, const ushort* A, int lda, const ushort* BT, void* C, int ldc,
                  const float* Add, int M, int N, int K, int l, int t0){
    int gx = cdiv_i(M, 128);
    int nwg = gx * (N >> 7);
    if (epi == 1) gemm_k<128,1><<<nwg, 256, 0, stream>>>(A, lda, BT, C, ldc, Add, M, N, K, gx, 0, l, t0, kcache, vcache, qbuf);
    if (epi == 2) gemm_k<128,2><<<nwg, 256, 0, stream>>>(A, lda, BT, C, ldc, Add, M, N, K, gx, 0, l, t0, kcache, vcache, qbuf);
    if (epi == 3) gemm_k<128,3><<<nwg, 256, 0, stream>>>(A, lda, BT, C, ldc, Add, M, N, K, gx, 0, l, t0, kcache, vcache, qbuf);
    if (epi == 4) gemm_k<128,4><<<nwg, 256, 0, stream>>>(A, lda, BT, C, ldc, Add, M, N, K, gx, 0, l, t0, kcache, vcache, qbuf);
  };
  // small-M split-K launcher + reduce
  auto gsmall = [&](int epi, const ushort* A, int lda, const ushort* BT, void* C, int ldc,
                    const float* Add, int M, int N, int K, int l, int t0){
    int KS = K / 256;
    int nwg = KS * (N >> 7);
    gemm_k<16,5><<<nwg, 256, 0, stream>>>(A, lda, BT, (void*)part, N, nullptr, M, N, K, 1, 256, l, t0, kcache, vcache, qbuf);
    int nred = cdiv_i(M * N, 256);
    if (epi == 1) sred_k<1><<<nred, 256, 0, stream>>>(part, KS, M, N, C, ldc, Add, l, t0, kcache, vcache, qbuf);
    if (epi == 2) sred_k<2><<<nred, 256, 0, stream>>>(part, KS, M, N, C, ldc, Add, l, t0, kcache, vcache, qbuf);
    if (epi == 4) sred_k<4><<<nred, 256, 0, stream>>>(part, KS, M, N, C, ldc, Add, l, t0, kcache, vcache, qbuf);
  };

  for (int c = 0; c < 7; c++){
    int t0 = ct0[c];
    int Tc = ct1[c] - t0;
    int M  = Tc * BB;
    long roff = (long)t0 * BB;
    bool big = (M >= 128);
    for (int l = 0; l < LL; l++){
      ln_k<<<dim3(M), dim3(256), 0, stream>>>(x, ln1g + l * DD, ln1b + l * DD, hbuf, roff);
      if (big) g128(4, hbuf + roff * DD, DD, wqkvT + (long)l * 3 * DD * DD, nullptr, 0, nullptr, M, 3 * DD, DD, l, t0);
      else   gsmall(4, hbuf + roff * DD, DD, wqkvT + (long)l * 3 * DD * DD, nullptr, 0, nullptr, M, 3 * DD, DD, l, t0);
      attn_k<<<dim3(cdiv_i(Tc, 4), HH, BB), dim3(256), 0, stream>>>(qbuf, kcache, vcache, obuf, l, t0, Tc);
      if (big) g128(1, obuf + roff * DD, DD, woT + (long)l * DD * DD, x + roff * DD, DD, x + roff * DD, M, DD, DD, l, t0);
      else   gsmall(1, obuf + roff * DD, DD, woT + (long)l * DD * DD, x + roff * DD, DD, x + roff * DD, M, DD, DD, l, t0);
      ln_k<<<dim3(M), dim3(256), 0, stream>>>(x, ln2g + l * DD, ln2b + l * DD, hbuf, roff);
      if (big) g128(2, hbuf + roff * DD, DD, w1T + (long)l * FFF * DD, gbuf + roff * FFF, FFF, nullptr, M, FFF, DD, l, t0);
      else   gsmall(2, hbuf + roff * DD, DD, w1T + (long)l * FFF * DD, gbuf + roff * FFF, FFF, nullptr, M, FFF, DD, l, t0);
      if (big) g128(1, gbuf + roff * FFF, FFF, w2T + (long)l * DD * FFF, x + roff * DD, DD, x + roff * DD, M, DD, FFF, l, t0);
      else   gsmall(1, gbuf + roff * FFF, FFF, w2T + (long)l * DD * FFF, x + roff * DD, DD, x + roff * DD, M, DD, FFF, l, t0);
    }
    ln_k<<<dim3(M), dim3(256), 0, stream>>>(x, lnfg, lnfb, hid, roff);
    if (c < 6)
      advance_k<<<dim3(DD / 256, BB), dim3(256), 0, stream>>>(hid, pe, x, out_emb, 64 + c);
  }

  // single deferred lm_head over all positions
  g128(3, hid, DD, lmT, out_logits, 0, nullptr, BB * SS, VV, DD, 0, 0);

  loss_rows_k<<<dim3(SS - 1, BB), dim3(256), 0, stream>>>(out_logits, labels, rowls);
  loss_final_k<<<dim3(1), dim3(256), 0, stream>>>(rowls, out_loss);
}

// Round 4
// 4623.737 us; speedup vs baseline: 1.1600x; 1.0359x over previous
//
#include <hip/hip_runtime.h>

static constexpr int BB  = 4;
static constexpr int SS  = 512;
static constexpr int DD  = 1024;
static constexpr int HH  = 16;
static constexpr int LL  = 4;
static constexpr int VV  = 32000;
static constexpr int DHH = 64;
static constexpr int FFF = 4096;

typedef short bf16x8  __attribute__((ext_vector_type(8)));
typedef short bf16x4v __attribute__((ext_vector_type(4)));
typedef float f32x4   __attribute__((ext_vector_type(4)));

__device__ __forceinline__ float b2f(ushort u){
  union { float f; unsigned int u32; } x; x.u32 = ((unsigned int)u) << 16; return x.f;
}
__device__ __forceinline__ ushort f2b(float f){
  union { float f; unsigned int u32; } x; x.f = f;
  unsigned int u = x.u32;
  return (ushort)((u + 0x7FFFu + ((u >> 16) & 1u)) >> 16);
}

// ---------------- weight convert + transpose: f32 [K][N] -> bf16 [N][K] ----------------
__global__ __launch_bounds__(256) void convT_k(const float* __restrict__ in, ushort* __restrict__ out,
                                               int K, int N, long inStride, long outStride)
{
  in  += (long)blockIdx.z * inStride;
  out += (long)blockIdx.z * outStride;
  __shared__ float tile[64][65];
  int n0 = blockIdx.x * 64, k0 = blockIdx.y * 64;
  int tid = threadIdx.x;
  int cc = tid & 63, rr = tid >> 6;
#pragma unroll
  for (int i = 0; i < 16; i++){
    int r = rr + i * 4;
    tile[r][cc] = in[(long)(k0 + r) * N + n0 + cc];
  }
  __syncthreads();
#pragma unroll
  for (int i = 0; i < 16; i++){
    int r = rr + i * 4;
    out[(long)(n0 + r) * K + k0 + cc] = f2b(tile[cc][r]);
  }
}

// ---------------- embedding (token-major x, b-major out_emb) ----------------
__global__ __launch_bounds__(256) void embed_k(const int* __restrict__ ids, const float* __restrict__ emb,
                                               const float* __restrict__ pe, float* __restrict__ x,
                                               float* __restrict__ oemb)
{
  int t = blockIdx.x, b = blockIdx.y, tid = threadIdx.x;
  int id = ids[b * SS + t];
  float4 ev = *((const float4*)(emb + (long)id * DD) + tid);
  float4 pv = *((const float4*)(pe  + (long)t  * DD) + tid);
  *((float4*)(x + (long)(t * BB + b) * DD) + tid) =
      make_float4(ev.x + pv.x, ev.y + pv.y, ev.z + pv.z, ev.w + pv.w);
  float* op = oemb + ((long)b * SS + t) * DD + tid * 4;   // d_out+4B: scalar stores
  op[0] = ev.x; op[1] = ev.y; op[2] = ev.z; op[3] = ev.w;
}

// ---------------- layernorm: f32 row -> bf16 row (row-indexed, token-major) ----------------
__global__ __launch_bounds__(256) void ln_k(const float* __restrict__ xin, const float* __restrict__ g,
                                            const float* __restrict__ bt, ushort* __restrict__ out, long row0)
{
  long row = row0 + blockIdx.x;
  int tid = threadIdx.x;
  const float* rp = xin + row * DD;
  float4 v = *(const float4*)(rp + tid * 4);
  float s1 = v.x + v.y + v.z + v.w;
  float s2 = v.x * v.x + v.y * v.y + v.z * v.z + v.w * v.w;
#pragma unroll
  for (int o = 32; o; o >>= 1){ s1 += __shfl_down(s1, o); s2 += __shfl_down(s2, o); }
  __shared__ float red[2][4];
  int wv = tid >> 6, lane = tid & 63;
  if (lane == 0){ red[0][wv] = s1; red[1][wv] = s2; }
  __syncthreads();
  s1 = red[0][0] + red[0][1] + red[0][2] + red[0][3];
  s2 = red[1][0] + red[1][1] + red[1][2] + red[1][3];
  float mean = s1 * (1.0f / DD);
  float var  = s2 * (1.0f / DD) - mean * mean;
  float rstd = rsqrtf(var + 1e-5f);
  float4 gv = *(const float4*)(g + tid * 4);
  float4 bv = *(const float4*)(bt + tid * 4);
  ushort4 o4;
  o4.x = f2b((v.x - mean) * rstd * gv.x + bv.x);
  o4.y = f2b((v.y - mean) * rstd * gv.y + bv.y);
  o4.z = f2b((v.z - mean) * rstd * gv.z + bv.z);
  o4.w = f2b((v.w - mean) * rstd * gv.w + bv.w);
  *(ushort4*)(out + row * DD + tid * 4) = o4;
}

// ---------------- shared epilogue (big GEMM path) ----------------
template<int EPI>
__device__ __forceinline__ void epi_store(float v, int grow, int ocol, void* Cv, int ldc,
                                          const float* Add, int t0, int l,
                                          ushort* kc, ushort* vc, ushort* qb)
{
  if constexpr (EPI == 1){
    float* Cf = (float*)Cv; long idx = (long)grow * ldc + ocol;
    Cf[idx] = v + Add[idx];
  } else if constexpr (EPI == 2){
    ushort* Cb = (ushort*)Cv; long idx = (long)grow * ldc + ocol;
    float tt = 0.7978845608028654f * (v + 0.044715f * v * v * v);
    Cb[idx] = f2b(0.5f * v * (1.0f + tanhf(tt)));
  } else if constexpr (EPI == 3){
    int t = t0 + (grow >> 2), b = grow & 3;
    ((float*)Cv)[((long)b * SS + t) * VV + ocol] = v;
  } else if constexpr (EPI == 4){
    if (ocol < DD){
      qb[((long)(t0 * BB + grow)) * DD + ocol] = f2b(v);
    } else {
      int t = t0 + (grow >> 2), b = grow & 3;
      int h = (ocol >> 6) & 15, d = ocol & 63;
      long dst = (((long)l * BB + b) * HH + h) * ((long)SS * DHH) + (long)t * DHH + d;
      if (ocol >= 2 * DD) vc[dst] = f2b(v); else kc[dst] = f2b(v);
    }
  }
}

// ---------------- big GEMM: BM=128 only (decode no longer uses gemm_k) ----------------
template<int EPI>
__global__ __launch_bounds__(256) void gemm_k(const ushort* __restrict__ A, int lda,
                                              const ushort* __restrict__ BT,
                                              void* Cv, int ldc,
                                              const float* Add,
                                              int M, int N, int K, int gx,
                                              int l, int t0,
                                              ushort* kc, ushort* vc, ushort* qb)
{
  constexpr int BM  = 128;
  constexpr int MFR = 4;   // 64/16
  constexpr int NFR = 4;
  __shared__ ushort As[BM][72];
  __shared__ ushort Bs[128][72];
  int tid = threadIdx.x;
  int wv = tid >> 6, lane = tid & 63;
  int wm = wv >> 1, wn = wv & 1;

  int nwg = gridDim.x, orig = blockIdx.x;
  int qq = nwg >> 3, rr8 = nwg & 7, xcd = orig & 7;
  int wgid = ((xcd < rr8) ? xcd * (qq + 1) : rr8 * (qq + 1) + (xcd - rr8) * qq) + (orig >> 3);

  int bx = wgid % gx, by = wgid / gx;
  int m0 = bx * BM, n0 = by * 128;

  f32x4 acc[MFR][NFR];
  f32x4 zz = {0.f, 0.f, 0.f, 0.f};
#pragma unroll
  for (int m = 0; m < MFR; m++)
#pragma unroll
    for (int n = 0; n < NFR; n++) acc[m][n] = zz;

  int g4 = (lane >> 4) * 4;
  int rA = lane & 15;

  for (int k0 = 0; k0 < K; k0 += 64){
#pragma unroll
    for (int i = 0; i < 4; i++){
      int r = (tid >> 3) + i * 32;
      int c = (tid & 7) * 8;
      uint4 val = make_uint4(0u, 0u, 0u, 0u);
      int gr = m0 + r;
      if (gr < M) val = *(const uint4*)(A + (long)gr * lda + k0 + c);
      *(uint4*)&As[r][c] = val;
    }
#pragma unroll
    for (int i = 0; i < 4; i++){
      int r = (tid >> 3) + i * 32;
      int c = (tid & 7) * 8;
      *(uint4*)&Bs[r][c] = *(const uint4*)(BT + (long)(n0 + r) * K + k0 + c);
    }
    __syncthreads();
#pragma unroll
    for (int kk = 0; kk < 64; kk += 32){
      bf16x8 af[MFR], bfr[NFR];
#pragma unroll
      for (int m = 0; m < MFR; m++){
        int row = wm * 64 + m * 16 + rA;
        bf16x4v lo = *(const bf16x4v*)&As[row][kk + g4];
        bf16x4v hi = *(const bf16x4v*)&As[row][kk + 16 + g4];
        af[m] = __builtin_shufflevector(lo, hi, 0, 1, 2, 3, 4, 5, 6, 7);
      }
#pragma unroll
      for (int n = 0; n < NFR; n++){
        int row = wn * 64 + n * 16 + rA;
        bf16x4v lo = *(const bf16x4v*)&Bs[row][kk + g4];
        bf16x4v hi = *(const bf16x4v*)&Bs[row][kk + 16 + g4];
        bfr[n] = __builtin_shufflevector(lo, hi, 0, 1, 2, 3, 4, 5, 6, 7);
      }
#pragma unroll
      for (int m = 0; m < MFR; m++)
#pragma unroll
        for (int n = 0; n < NFR; n++)
          acc[m][n] = __builtin_amdgcn_mfma_f32_16x16x32_bf16(af[m], bfr[n], acc[m][n], 0, 0, 0);
    }
    __syncthreads();
  }

  int r4 = (lane >> 4) * 4;
#pragma unroll
  for (int m = 0; m < MFR; m++){
#pragma unroll
    for (int n = 0; n < NFR; n++){
      int orow = wm * 64 + m * 16 + r4;
      int ocol = n0 + wn * 64 + n * 16 + rA;
#pragma unroll
      for (int r = 0; r < 4; r++){
        int grow = m0 + orow + r;
        if (grow < M)
          epi_store<EPI>(acc[m][n][r], grow, ocol, Cv, ldc, Add, t0, l, kc, vc, qb);
      }
    }
  }
}

// ---------------- decode GEMV (M=4): fused LN + epilogue, single dispatch ----------------
// TYPE 0: LN1(x) -> qkv -> qbuf + kv cache      TYPE 1: obuf -> Wo -> x += res
// TYPE 2: LN2(x) -> W1 -> gelu -> gbuf          TYPE 3: gbuf (K=4096) -> W2 -> x += res
template<int TYPE>
__global__ __launch_bounds__(256) void dec_gemv_k(const float* xf, const ushort* ab,
                                                  const float* g, const float* bt,
                                                  const ushort* WT, float* x,
                                                  ushort* qb, ushort* kc, ushort* vc, ushort* gb,
                                                  int l, int pos)
{
  constexpr int K   = (TYPE == 3) ? FFF : DD;
  constexpr int NCH = K / 1024;
  int tid = threadIdx.x, wid = tid >> 6, lane = tid & 63;
  int n_base = blockIdx.x * 16 + wid * 4;

  float acc[4][4];   // [col][row]
#pragma unroll
  for (int c = 0; c < 4; c++)
#pragma unroll
    for (int r = 0; r < 4; r++) acc[c][r] = 0.f;

#pragma unroll
  for (int ch = 0; ch < NCH; ch++){
    int ks = ch * 1024 + lane * 16;
    float a[4][16];
    if constexpr (TYPE == 0 || TYPE == 2){
      // load f32 x rows + LN in registers
#pragma unroll
      for (int r = 0; r < 4; r++){
        const float* rp = xf + (long)(pos * BB + r) * DD + ks;
#pragma unroll
        for (int q = 0; q < 4; q++){
          float4 v = *(const float4*)(rp + q * 4);
          a[r][q*4+0] = v.x; a[r][q*4+1] = v.y; a[r][q*4+2] = v.z; a[r][q*4+3] = v.w;
        }
      }
      float gj[16], bj[16];
#pragma unroll
      for (int q = 0; q < 4; q++){
        float4 gv = *(const float4*)(g  + ks + q * 4);
        float4 bv = *(const float4*)(bt + ks + q * 4);
        gj[q*4+0]=gv.x; gj[q*4+1]=gv.y; gj[q*4+2]=gv.z; gj[q*4+3]=gv.w;
        bj[q*4+0]=bv.x; bj[q*4+1]=bv.y; bj[q*4+2]=bv.z; bj[q*4+3]=bv.w;
      }
#pragma unroll
      for (int r = 0; r < 4; r++){
        float s1 = 0.f, s2 = 0.f;
#pragma unroll
        for (int j = 0; j < 16; j++){ s1 += a[r][j]; s2 += a[r][j] * a[r][j]; }
#pragma unroll
        for (int o = 32; o; o >>= 1){ s1 += __shfl_xor(s1, o); s2 += __shfl_xor(s2, o); }
        float mean = s1 * (1.0f / DD);
        float var  = s2 * (1.0f / DD) - mean * mean;
        float rstd = rsqrtf(var + 1e-5f);
#pragma unroll
        for (int j = 0; j < 16; j++)
          a[r][j] = b2f(f2b((a[r][j] - mean) * rstd * gj[j] + bj[j]));   // match bf16 hbuf path
      }
    } else {
      constexpr int AD = (TYPE == 3) ? FFF : DD;
#pragma unroll
      for (int r = 0; r < 4; r++){
        const ushort* rp = ab + (long)(pos * BB + r) * AD + ks;
        uint4 pa = *(const uint4*)rp;
        uint4 pb = *(const uint4*)(rp + 8);
        const unsigned int w[8] = {pa.x, pa.y, pa.z, pa.w, pb.x, pb.y, pb.z, pb.w};
#pragma unroll
        for (int q = 0; q < 8; q++){
          a[r][q*2]   = b2f((ushort)(w[q] & 0xffff));
          a[r][q*2+1] = b2f((ushort)(w[q] >> 16));
        }
      }
    }
#pragma unroll
    for (int c = 0; c < 4; c++){
      const ushort* wp = WT + (long)(n_base + c) * K + ks;
      uint4 pa = *(const uint4*)wp;
      uint4 pb = *(const uint4*)(wp + 8);
      const unsigned int w[8] = {pa.x, pa.y, pa.z, pa.w, pb.x, pb.y, pb.z, pb.w};
      float wf[16];
#pragma unroll
      for (int q = 0; q < 8; q++){
        wf[q*2]   = b2f((ushort)(w[q] & 0xffff));
        wf[q*2+1] = b2f((ushort)(w[q] >> 16));
      }
#pragma unroll
      for (int r = 0; r < 4; r++){
        float s = 0.f;
#pragma unroll
        for (int j = 0; j < 16; j++) s += a[r][j] * wf[j];
        acc[c][r] += s;
      }
    }
  }

#pragma unroll
  for (int c = 0; c < 4; c++)
#pragma unroll
    for (int r = 0; r < 4; r++)
#pragma unroll
      for (int o = 32; o; o >>= 1) acc[c][r] += __shfl_xor(acc[c][r], o);

  if (lane < 4){
    int r = lane;
    long Rrow = (long)(pos * BB + r);
#pragma unroll
    for (int c = 0; c < 4; c++){
      int n = n_base + c;
      float v = acc[c][r];
      if constexpr (TYPE == 0){
        if (n < DD){
          qb[Rrow * DD + n] = f2b(v);
        } else if (n < 2 * DD){
          int h = (n - DD) >> 6, d = n & 63;
          kc[(((long)l * BB + r) * HH + h) * ((long)SS * DHH) + (long)pos * DHH + d] = f2b(v);
        } else {
          int h = (n - 2 * DD) >> 6, d = n & 63;
          vc[(((long)l * BB + r) * HH + h) * ((long)SS * DHH) + (long)pos * DHH + d] = f2b(v);
        }
      } else if constexpr (TYPE == 2){
        float tt = 0.7978845608028654f * (v + 0.044715f * v * v * v);
        gb[Rrow * FFF + n] = f2b(0.5f * v * (1.0f + tanhf(tt)));
      } else {
        long idx = Rrow * DD + n;
        x[idx] = x[idx] + v;
      }
    }
  }
}

// ---------------- decode final: lnf + hid write + advance, one block ----------------
__global__ __launch_bounds__(256) void dec_final_k(const float* xf, const float* g, const float* bt,
                                                   const float* pe, ushort* hid, float* x,
                                                   float* oemb, int pos)
{
  int wid = threadIdx.x >> 6, lane = threadIdx.x & 63;   // wid = batch row
  long R = (long)(pos * BB + wid);
  const float* rp = xf + R * DD + lane * 16;
  float a[16];
#pragma unroll
  for (int q = 0; q < 4; q++){
    float4 v = *(const float4*)(rp + q * 4);
    a[q*4+0] = v.x; a[q*4+1] = v.y; a[q*4+2] = v.z; a[q*4+3] = v.w;
  }
  float s1 = 0.f, s2 = 0.f;
#pragma unroll
  for (int j = 0; j < 16; j++){ s1 += a[j]; s2 += a[j] * a[j]; }
#pragma unroll
  for (int o = 32; o; o >>= 1){ s1 += __shfl_xor(s1, o); s2 += __shfl_xor(s2, o); }
  float mean = s1 * (1.0f / DD);
  float var  = s2 * (1.0f / DD) - mean * mean;
  float rstd = rsqrtf(var + 1e-5f);
  int pn = pos + 1;
#pragma unroll
  for (int j = 0; j < 16; j++){
    int d = lane * 16 + j;
    ushort hb = f2b((a[j] - mean) * rstd * g[d] + bt[d]);
    hid[R * DD + d] = hb;
    float hv = b2f(hb);
    oemb[((long)wid * SS + pn) * DD + d] = hv;
    x[((long)(pn * BB + wid)) * DD + d] = hv + pe[(long)pn * DD + d];
  }
}

// ---------------- attention (token-major q/o, cached k/v) ----------------
__global__ __launch_bounds__(256) void attn_k(const ushort* __restrict__ qb, const ushort* __restrict__ kc,
                                              const ushort* __restrict__ vc, ushort* __restrict__ o,
                                              int l, int t0, int Tc)
{
  __shared__ float sc[4][512];
  __shared__ float qs[4][64];
  int tid = threadIdx.x, wv = tid >> 6, lane = tid & 63;
  int b = blockIdx.z, h = blockIdx.y;
  int qrow = blockIdx.x * 4 + wv;
  bool act = qrow < Tc;
  int tq = t0 + qrow;
  long kvoff = (((long)l * BB + b) * HH + h) * ((long)SS * DHH);
  const ushort* kb = kc + kvoff;
  const ushort* vb = vc + kvoff;
  if (act) qs[wv][lane] = b2f(qb[((long)(tq * BB + b)) * DD + h * DHH + lane]);
  __syncthreads();
  int nk = act ? (tq + 1) : 0;
  float m = -3.0e38f;
  for (int key = lane; key < nk; key += 64){
    const ushort* kp = kb + (long)key * DHH;
    float s = 0.f;
#pragma unroll
    for (int j = 0; j < 8; j++){
      uint4 kvv = *(const uint4*)(kp + j * 8);
      s += qs[wv][j*8+0] * b2f((ushort)(kvv.x & 0xffff));
      s += qs[wv][j*8+1] * b2f((ushort)(kvv.x >> 16));
      s += qs[wv][j*8+2] * b2f((ushort)(kvv.y & 0xffff));
      s += qs[wv][j*8+3] * b2f((ushort)(kvv.y >> 16));
      s += qs[wv][j*8+4] * b2f((ushort)(kvv.z & 0xffff));
      s += qs[wv][j*8+5] * b2f((ushort)(kvv.z >> 16));
      s += qs[wv][j*8+6] * b2f((ushort)(kvv.w & 0xffff));
      s += qs[wv][j*8+7] * b2f((ushort)(kvv.w >> 16));
    }
    s *= 0.125f;
    sc[wv][key] = s;
    m = fmaxf(m, s);
  }
#pragma unroll
  for (int off = 32; off; off >>= 1) m = fmaxf(m, __shfl_xor(m, off));
  float ssum = 0.f;
  for (int key = lane; key < nk; key += 64){
    float p = expf(sc[wv][key] - m);
    sc[wv][key] = p;
    ssum += p;
  }
#pragma unroll
  for (int off = 32; off; off >>= 1) ssum += __shfl_xor(ssum, off);
  __syncthreads();
  float accv = 0.f;
  for (int key = 0; key < nk; key++)
    accv += sc[wv][key] * b2f(vb[(long)key * DHH + lane]);
  if (act) o[((long)(tq * BB + b)) * DD + h * DHH + lane] = f2b(accv / ssum);
}

// ---------------- feedback (big-chunk boundary only) ----------------
__global__ __launch_bounds__(256) void advance_k(const ushort* __restrict__ hid, const float* __restrict__ pe,
                                                 float* __restrict__ x, float* __restrict__ oemb, int pos)
{
  int d = blockIdx.x * 256 + threadIdx.x;
  int b = blockIdx.y;
  float hv = b2f(hid[((long)((pos - 1) * BB + b)) * DD + d]);
  oemb[((long)b * SS + pos) * DD + d] = hv;
  x[((long)(pos * BB + b)) * DD + d] = hv + pe[(long)pos * DD + d];
}

// ---------------- loss ----------------
__global__ __launch_bounds__(256) void loss_rows_k(const float* __restrict__ logits, const int* __restrict__ labels,
                                                   float* __restrict__ rowloss)
{
  int t = blockIdx.x, b = blockIdx.y, tid = threadIdx.x;
  const float* row = logits + ((long)b * SS + t) * VV;
  float m = -3.0e38f, s = 0.f;
  for (int i = tid; i < VV; i += 256){
    float v = row[i];
    if (v > m){ s = s * expf(m - v) + 1.f; m = v; }
    else s += expf(v - m);
  }
  __shared__ float sm[256], ssb[256];
  sm[tid] = m; ssb[tid] = s;
  __syncthreads();
  if (tid == 0){
    float M = -3.0e38f;
    for (int i = 0; i < 256; i++) M = fmaxf(M, sm[i]);
    float Ssum = 0.f;
    for (int i = 0; i < 256; i++) Ssum += ssb[i] * expf(sm[i] - M);
    int lab = labels[b * SS + t + 1];
    float xl = row[lab];
    rowloss[b * (SS - 1) + t] = (M + logf(Ssum)) - xl;
  }
}

__global__ __launch_bounds__(256) void loss_final_k(const float* __restrict__ rowloss, float* __restrict__ out)
{
  int tid = threadIdx.x;
  float s = 0.f;
  for (int i = tid; i < BB * (SS - 1); i += 256) s += rowloss[i];
#pragma unroll
  for (int o = 32; o; o >>= 1) s += __shfl_down(s, o);
  __shared__ float red[4];
  if ((tid & 63) == 0) red[tid >> 6] = s;
  __syncthreads();
  if (tid == 0) out[0] = (red[0] + red[1] + red[2] + red[3]) / (float)(BB * (SS - 1));
}

// ---------------- host ----------------
static inline int cdiv_i(int a, int b){ return (a + b - 1) / b; }

extern "C" void kernel_launch(void* const* d_in, const int* in_sizes, int n_in,
                              void* d_out, int out_size, void* d_ws, size_t ws_size,
                              hipStream_t stream)
{
  (void)in_sizes; (void)n_in; (void)out_size; (void)ws_size;
  const int*   ids    = (const int*)d_in[0];
  const int*   labels = (const int*)d_in[2];
  const float* emb    = (const float*)d_in[4];
  const float* pe     = (const float*)d_in[5];
  const float* Wqkv   = (const float*)d_in[6];
  const float* Wo     = (const float*)d_in[7];
  const float* W1     = (const float*)d_in[8];
  const float* W2     = (const float*)d_in[9];
  const float* ln1g   = (const float*)d_in[10];
  const float* ln1b   = (const float*)d_in[11];
  const float* ln2g   = (const float*)d_in[12];
  const float* ln2b   = (const float*)d_in[13];
  const float* lnfg   = (const float*)d_in[14];
  const float* lnfb   = (const float*)d_in[15];
  const float* lm     = (const float*)d_in[16];

  float* out_loss   = (float*)d_out;
  float* out_emb    = out_loss + 1;
  float* out_logits = out_emb + (size_t)BB * SS * DD;

  char* wsp = (char*)d_ws;
  size_t off = 0;
  auto alloc = [&](size_t bytes) -> void* {
    void* p = wsp + off; off += (bytes + 255) & ~(size_t)255; return p;
  };
  ushort* wqkvT = (ushort*)alloc((size_t)LL * 3 * DD * DD * 2);
  ushort* woT   = (ushort*)alloc((size_t)LL * DD * DD * 2);
  ushort* w1T   = (ushort*)alloc((size_t)LL * FFF * DD * 2);
  ushort* w2T   = (ushort*)alloc((size_t)LL * DD * FFF * 2);
  ushort* lmT   = (ushort*)alloc((size_t)VV * DD * 2);
  float*  x     = (float*)alloc((size_t)BB * SS * DD * 4);
  ushort* hbuf  = (ushort*)alloc((size_t)BB * SS * DD * 2);
  ushort* qbuf  = (ushort*)alloc((size_t)BB * SS * DD * 2);
  ushort* obuf  = (ushort*)alloc((size_t)BB * SS * DD * 2);
  ushort* gbuf  = (ushort*)alloc((size_t)BB * SS * FFF * 2);
  ushort* hid   = (ushort*)alloc((size_t)BB * SS * DD * 2);
  ushort* kcache= (ushort*)alloc((size_t)LL * BB * SS * DD * 2);
  ushort* vcache= (ushort*)alloc((size_t)LL * BB * SS * DD * 2);
  float*  rowls = (float*)alloc((size_t)BB * (SS - 1) * 4);

  convT_k<<<dim3(3 * DD / 64, DD / 64, LL), dim3(256), 0, stream>>>(Wqkv, wqkvT, DD, 3 * DD, (long)DD * 3 * DD, (long)3 * DD * DD);
  convT_k<<<dim3(DD / 64, DD / 64, LL),     dim3(256), 0, stream>>>(Wo,   woT,  DD, DD,     (long)DD * DD,     (long)DD * DD);
  convT_k<<<dim3(FFF / 64, DD / 64, LL),    dim3(256), 0, stream>>>(W1,   w1T,  DD, FFF,    (long)DD * FFF,    (long)FFF * DD);
  convT_k<<<dim3(DD / 64, FFF / 64, LL),    dim3(256), 0, stream>>>(W2,   w2T,  FFF, DD,    (long)FFF * DD,    (long)DD * FFF);
  convT_k<<<dim3(VV / 64, DD / 64, 1),      dim3(256), 0, stream>>>(lm,   lmT,  DD, VV,     0, 0);

  embed_k<<<dim3(SS, BB), dim3(256), 0, stream>>>(ids, emb, pe, x, out_emb);

  const int ct0[7] = {0, 64, 65, 66, 67, 68, 69};
  const int ct1[7] = {64, 65, 66, 67, 68, 69, 512};

  auto g128 = [&](int epi, const ushort* A, int lda, const ushort* BT, void* C, int ldc,
                  const float* Add, int M, int N, int K, int l, int t0){
    int gx = cdiv_i(M, 128);
    int nwg = gx * (N >> 7);
    if (epi == 1) gemm_k<1><<<nwg, 256, 0, stream>>>(A, lda, BT, C, ldc, Add, M, N, K, gx, l, t0, kcache, vcache, qbuf);
    if (epi == 2) gemm_k<2><<<nwg, 256, 0, stream>>>(A, lda, BT, C, ldc, Add, M, N, K, gx, l, t0, kcache, vcache, qbuf);
    if (epi == 3) gemm_k<3><<<nwg, 256, 0, stream>>>(A, lda, BT, C, ldc, Add, M, N, K, gx, l, t0, kcache, vcache, qbuf);
    if (epi == 4) gemm_k<4><<<nwg, 256, 0, stream>>>(A, lda, BT, C, ldc, Add, M, N, K, gx, l, t0, kcache, vcache, qbuf);
  };

  for (int c = 0; c < 7; c++){
    int t0 = ct0[c];
    int Tc = ct1[c] - t0;
    int M  = Tc * BB;
    long roff = (long)t0 * BB;

    if (Tc == 1){
      // ---- fused decode step: 5 dispatches per layer + 1 final ----
      int pos = t0;
      for (int l = 0; l < LL; l++){
        dec_gemv_k<0><<<dim3(3 * DD / 16), dim3(256), 0, stream>>>(x, nullptr, ln1g + l * DD, ln1b + l * DD,
            wqkvT + (long)l * 3 * DD * DD, nullptr, qbuf, kcache, vcache, nullptr, l, pos);
        attn_k<<<dim3(1, HH, BB), dim3(64), 0, stream>>>(qbuf, kcache, vcache, obuf, l, t0, Tc);
        dec_gemv_k<1><<<dim3(DD / 16), dim3(256), 0, stream>>>(nullptr, obuf, nullptr, nullptr,
            woT + (long)l * DD * DD, x, nullptr, nullptr, nullptr, nullptr, l, pos);
        dec_gemv_k<2><<<dim3(FFF / 16), dim3(256), 0, stream>>>(x, nullptr, ln2g + l * DD, ln2b + l * DD,
            w1T + (long)l * FFF * DD, nullptr, nullptr, nullptr, nullptr, gbuf, l, pos);
        dec_gemv_k<3><<<dim3(DD / 16), dim3(256), 0, stream>>>(nullptr, gbuf, nullptr, nullptr,
            w2T + (long)l * DD * FFF, x, nullptr, nullptr, nullptr, nullptr, l, pos);
      }
      dec_final_k<<<dim3(1), dim3(256), 0, stream>>>(x, lnfg, lnfb, pe, hid, x, out_emb, pos);
    } else {
      for (int l = 0; l < LL; l++){
        ln_k<<<dim3(M), dim3(256), 0, stream>>>(x, ln1g + l * DD, ln1b + l * DD, hbuf, roff);
        g128(4, hbuf + roff * DD, DD, wqkvT + (long)l * 3 * DD * DD, nullptr, 0, nullptr, M, 3 * DD, DD, l, t0);
        attn_k<<<dim3(cdiv_i(Tc, 4), HH, BB), dim3(256), 0, stream>>>(qbuf, kcache, vcache, obuf, l, t0, Tc);
        g128(1, obuf + roff * DD, DD, woT + (long)l * DD * DD, x + roff * DD, DD, x + roff * DD, M, DD, DD, l, t0);
        ln_k<<<dim3(M), dim3(256), 0, stream>>>(x, ln2g + l * DD, ln2b + l * DD, hbuf, roff);
        g128(2, hbuf + roff * DD, DD, w1T + (long)l * FFF * DD, gbuf + roff * FFF, FFF, nullptr, M, FFF, DD, l, t0);
        g128(1, gbuf + roff * FFF, FFF, w2T + (long)l * DD * FFF, x + roff * DD, DD, x + roff * DD, M, DD, FFF, l, t0);
      }
      ln_k<<<dim3(M), dim3(256), 0, stream>>>(x, lnfg, lnfb, hid, roff);
      if (c == 0)
        advance_k<<<dim3(DD / 256, BB), dim3(256), 0, stream>>>(hid, pe, x, out_emb, 64);
    }
  }

  // single deferred lm_head over all positions
  g128(3, hid, DD, lmT, out_logits, 0, nullptr, BB * SS, VV, DD, 0, 0);

  loss_rows_k<<<dim3(SS - 1, BB), dim3(256), 0, stream>>>(out_logits, labels, rowls);
  loss_final_k<<<dim3(1), dim3(256), 0, stream>>>(rowls, out_loss);
}